// Round 8
// baseline (327.951 us; speedup 1.0000x reference)
//
#include <hip/hip_runtime.h>
#include <hip/hip_fp16.h>

#define FDIM 256
#define ALPHA 0.2f

typedef _Float16 half8 __attribute__((ext_vector_type(8)));
typedef float floatx4 __attribute__((ext_vector_type(4)));

// ---- prep W (fp16 chunked W^T image) + edge histogram, fused ---------------
__global__ __launch_bounds__(256) void prep_hist(const float* __restrict__ W,
                                                 _Float16* __restrict__ wswz,
                                                 const int* __restrict__ edge,
                                                 int* __restrict__ deg, int E) {
  if (blockIdx.x < 32) {
    const int g = blockIdx.x * 256 + threadIdx.x;  // 0..8191
    const int kc = g >> 11, L = g & 2047;
    const int n = L >> 3, c = L & 7;
    half8 hv;
#pragma unroll
    for (int j = 0; j < 8; ++j)
      hv[j] = (_Float16)W[(size_t)(kc * 64 + c * 8 + j) * 256 + n];
    *(half8*)(wswz + (size_t)g * 8) = hv;
  } else {
    const int e = (blockIdx.x - 32) * 256 + threadIdx.x;
    if (e < E) atomicAdd(&deg[edge[e]], 1);
  }
}

// ---- GEMM h = x@W, MFMA fp16; epilogue transposes via LDS for wide stores --
#define HT_STRIDE 264
__global__ __launch_bounds__(256) void gemm_mfma(
    const float* __restrict__ x, const _Float16* __restrict__ wswz,
    const float* __restrict__ a, _Float16* __restrict__ h,
    float* __restrict__ s, float* __restrict__ t, int M) {
  __shared__ __align__(16) _Float16 smem[64 * HT_STRIDE];  // 33.8 KB
  _Float16* As = smem;
  const int tid = threadIdx.x;
  const int w = tid >> 6, l = tid & 63;
  const int l15 = l & 15, q = l >> 4;
  const int row0 = blockIdx.x * 64;

  floatx4 acc[4][4];
#pragma unroll
  for (int mt = 0; mt < 4; ++mt)
#pragma unroll
    for (int nt = 0; nt < 4; ++nt) acc[mt][nt] = (floatx4){0.f, 0.f, 0.f, 0.f};

  const int id0 = tid, id1 = 256 + tid;
  const int m0 = id0 >> 3, c0 = (id0 & 7) ^ (m0 & 7);
  const int m1 = id1 >> 3, c1 = (id1 & 7) ^ (m1 & 7);
  const int r0 = row0 + m0, r1 = row0 + m1;

  float4 pf[2][2];
  auto loadA = [&](int kc) {
    pf[0][0] = pf[0][1] = pf[1][0] = pf[1][1] = make_float4(0.f, 0.f, 0.f, 0.f);
    if (r0 < M) {
      const float4* p = (const float4*)(x + (size_t)r0 * 256 + kc * 64 + c0 * 8);
      pf[0][0] = p[0];
      pf[0][1] = p[1];
    }
    if (r1 < M) {
      const float4* p = (const float4*)(x + (size_t)r1 * 256 + kc * 64 + c1 * 8);
      pf[1][0] = p[0];
      pf[1][1] = p[1];
    }
  };
  auto storeA = [&]() {
#pragma unroll
    for (int hf = 0; hf < 2; ++hf) {
      half8 hv;
      hv[0] = (_Float16)pf[hf][0].x; hv[1] = (_Float16)pf[hf][0].y;
      hv[2] = (_Float16)pf[hf][0].z; hv[3] = (_Float16)pf[hf][0].w;
      hv[4] = (_Float16)pf[hf][1].x; hv[5] = (_Float16)pf[hf][1].y;
      hv[6] = (_Float16)pf[hf][1].z; hv[7] = (_Float16)pf[hf][1].w;
      *(half8*)(As + (size_t)(hf * 256 + tid) * 8) = hv;
    }
  };

  loadA(0);
  for (int kc = 0; kc < 4; ++kc) {
    storeA();
    half8 bf[2][4];
#pragma unroll
    for (int ks = 0; ks < 2; ++ks) {
      const int c = ks * 4 + q;
#pragma unroll
      for (int nt = 0; nt < 4; ++nt) {
        const int n = w * 64 + nt * 16 + l15;
        bf[ks][nt] = *(const half8*)(wswz + (size_t)(kc * 2048 + n * 8 + c) * 8);
      }
    }
    __syncthreads();
    if (kc < 3) loadA(kc + 1);
#pragma unroll
    for (int ks = 0; ks < 2; ++ks) {
      const int c = ks * 4 + q;
      half8 af[4];
#pragma unroll
      for (int mt = 0; mt < 4; ++mt) {
        const int m = mt * 16 + l15;
        af[mt] = *(const half8*)(As + (size_t)(m * 8 + (c ^ (m & 7))) * 8);
      }
#pragma unroll
      for (int mt = 0; mt < 4; ++mt)
#pragma unroll
        for (int nt = 0; nt < 4; ++nt)
          acc[mt][nt] = __builtin_amdgcn_mfma_f32_16x16x32_f16(
              af[mt], bf[ks][nt], acc[mt][nt], 0, 0, 0);
    }
    __syncthreads();
  }

  // epilogue: C/D -> LDS row-major -> coalesced 16B stores
#pragma unroll
  for (int mt = 0; mt < 4; ++mt)
#pragma unroll
    for (int nt = 0; nt < 4; ++nt)
#pragma unroll
      for (int r = 0; r < 4; ++r)
        smem[(size_t)(mt * 16 + q * 4 + r) * HT_STRIDE + w * 64 + nt * 16 +
             l15] = (_Float16)acc[mt][nt][r];
  __syncthreads();

  const int w8 = tid >> 5;
  const int colh = (tid & 31) * 8;
#pragma unroll
  for (int p = 0; p < 8; ++p) {
    const int rl = p * 8 + w8;
    const int row = row0 + rl;
    if (row < M)
      *(half8*)(h + (size_t)row * 256 + colh) =
          *(const half8*)(smem + (size_t)rl * HT_STRIDE + colh);
  }

  // s/t from LDS tile
  const int r8 = tid >> 2, seg = tid & 3;
  float sp = 0.f, tp = 0.f;
#pragma unroll
  for (int c8 = 0; c8 < 8; ++c8) {
    const int col = seg * 64 + c8 * 8;
    const half8 hv = *(const half8*)(smem + (size_t)r8 * HT_STRIDE + col);
    const float4 a0 = *(const float4*)(a + col);
    const float4 a1 = *(const float4*)(a + col + 4);
    const float4 b0 = *(const float4*)(a + 256 + col);
    const float4 b1 = *(const float4*)(a + 256 + col + 4);
    sp += (float)hv[0] * a0.x + (float)hv[1] * a0.y + (float)hv[2] * a0.z +
          (float)hv[3] * a0.w + (float)hv[4] * a1.x + (float)hv[5] * a1.y +
          (float)hv[6] * a1.z + (float)hv[7] * a1.w;
    tp += (float)hv[0] * b0.x + (float)hv[1] * b0.y + (float)hv[2] * b0.z +
          (float)hv[3] * b0.w + (float)hv[4] * b1.x + (float)hv[5] * b1.y +
          (float)hv[6] * b1.z + (float)hv[7] * b1.w;
  }
  sp += __shfl_xor(sp, 1);
  sp += __shfl_xor(sp, 2);
  tp += __shfl_xor(tp, 1);
  tp += __shfl_xor(tp, 2);
  if (seg == 0 && row0 + r8 < M) {
    s[row0 + r8] = sp;
    t[row0 + r8] = tp;
  }
}

// ---- single-launch scan: per-block scan + predecessor-chain lookback -------
// flags[b] = 0 (not ready) or inclusive-prefix-through-b + 1. 49 blocks all
// co-resident (<< 256 CUs), so spinning on b-1 cannot deadlock.
__global__ __launch_bounds__(1024) void scan_one(const int* __restrict__ deg,
                                                 int* __restrict__ rowstart,
                                                 int* __restrict__ rsc,
                                                 int* __restrict__ flags,
                                                 int n, int nb) {
  const int tid = threadIdx.x;
  const int b = blockIdx.x;
  const int i = b * 1024 + tid;
  const int val = (i < n) ? deg[i] : 0;
  const int lane = tid & 63, wv = tid >> 6;
  int v = val;
#pragma unroll
  for (int off = 1; off < 64; off <<= 1) {
    const int o = __shfl_up(v, off);
    if (lane >= off) v += o;
  }
  __shared__ int wsum[16];
  __shared__ int woff[16];
  __shared__ int sbase;
  if (lane == 63) wsum[wv] = v;
  __syncthreads();
  if (tid < 16) {
    int wv2 = wsum[tid];
#pragma unroll
    for (int off = 1; off < 16; off <<= 1) {
      const int o = __shfl_up(wv2, off);
      if (tid >= off) wv2 += o;
    }
    woff[tid] = wv2;
  }
  __syncthreads();
  const int incl = v + (wv ? woff[wv - 1] : 0);
  const int aggregate = woff[15];
  if (tid == 0) {
    int base = 0;
    if (b > 0) {
      int f;
      do {
        f = __hip_atomic_load(&flags[b - 1], __ATOMIC_ACQUIRE,
                              __HIP_MEMORY_SCOPE_AGENT);
      } while (f == 0);
      base = f - 1;
    }
    __hip_atomic_store(&flags[b], base + aggregate + 1, __ATOMIC_RELEASE,
                       __HIP_MEMORY_SCOPE_AGENT);
    sbase = base;
  }
  __syncthreads();
  const int base = sbase;
  if (i < n) {
    const int ex = base + incl - val;
    rowstart[i] = ex;
    rsc[i] = ex;
  }
  if (b == nb - 1 && tid == 0) rowstart[n] = base + aggregate;
}

// ---- scatter: pure CSR permutation (no s/t, 4B payload) --------------------
__global__ void scatter_kernel(const int* __restrict__ edge,
                               int* __restrict__ rsc, int* __restrict__ sdst,
                               int E) {
  const int e = blockIdx.x * 256 + threadIdx.x;
  if (e < E) {
    const int src = edge[e];
    const int dst = edge[E + e];
    const int pos = atomicAdd(&rsc[src], 1);
    sdst[pos] = dst;
  }
}

// ---- aggregation: wave = 2 edges/iter, lane = 8 features; e computed inline
__global__ __launch_bounds__(256) void agg_kernel(
    const _Float16* __restrict__ h, const float* __restrict__ s,
    const float* __restrict__ t, const int* __restrict__ rowstart,
    const int* __restrict__ sdst, float* __restrict__ out, int n) {
  const int w = threadIdx.x >> 6, l = threadIdx.x & 63;
  const int row = blockIdx.x * 4 + w;
  if (row >= n) return;
  const int start = rowstart[row], end = rowstart[row + 1];
  const float srow = s[row];
  const int half = l >> 5;           // 0: edge j, 1: edge j+1
  const int lh = l & 31;             // lane within half
  const size_t fo = (size_t)lh * 8;  // 8 features = 16 B
  float acc[8] = {};
  float rs = 0.f;
  int j = start;
  for (; j + 8 <= end; j += 8) {
#pragma unroll
    for (int u = 0; u < 4; ++u) {
      const int d = sdst[j + u * 2 + half];
      const float logit = srow + t[d];
      const float lr = logit > 0.f ? logit : ALPHA * logit;
      const float e = __expf(-lr);
      const half8 v = *(const half8*)(h + (size_t)d * 256 + fo);
      rs += e;
#pragma unroll
      for (int k = 0; k < 8; ++k) acc[k] += e * (float)v[k];
    }
  }
  for (; j < end; j += 2) {
    const int idx = j + half;
    const bool valid = idx < end;
    const int d = valid ? sdst[idx] : 0;
    const float logit = srow + t[d];
    const float lr = logit > 0.f ? logit : ALPHA * logit;
    const float e = valid ? __expf(-lr) : 0.f;
    const half8 v = *(const half8*)(h + (size_t)d * 256 + fo);
    rs += e;
#pragma unroll
    for (int k = 0; k < 8; ++k) acc[k] += e * (float)v[k];
  }
  rs += __shfl_xor(rs, 32);
#pragma unroll
  for (int k = 0; k < 8; ++k) acc[k] += __shfl_xor(acc[k], 32);
  const float inv = 1.f / rs;
  float4 o;
#pragma unroll
  for (int k = 0; k < 4; ++k) {
    const float vv = acc[half * 4 + k] * inv;
    (&o.x)[k] = vv > 0.f ? vv : 0.f;
  }
  *(float4*)(out + (size_t)row * 256 + lh * 8 + half * 4) = o;
}

extern "C" void kernel_launch(void* const* d_in, const int* in_sizes, int n_in,
                              void* d_out, int out_size, void* d_ws,
                              size_t ws_size, hipStream_t stream) {
  const float* x = (const float*)d_in[0];
  const int* edge = (const int*)d_in[1];
  const float* W = (const float*)d_in[2];
  const float* a = (const float*)d_in[3];
  float* out = (float*)d_out;
  const int N = in_sizes[0] / FDIM;  // 50000
  const int E = in_sizes[1] / 2;     // 850000
  const int NB = (N + 1023) / 1024;  // 49

  _Float16* h = (_Float16*)d_ws;          // N*256 fp16
  _Float16* wswz = h + (size_t)N * FDIM;  // 65536 halves (128 KB)
  float* s = (float*)(wswz + 8192 * 8);   // N
  float* t = s + N;                       // N
  int* deg = (int*)(t + N);               // N  } one memset covers
  int* flags = deg + N;                   // 64 } deg + flags
  int* rsc = flags + 64;                  // N
  int* rowstart = rsc + N;                // N+2
  int* sdst = rowstart + N + 2;           // E

  hipMemsetAsync(deg, 0, (size_t)(N + 64) * sizeof(int), stream);

  prep_hist<<<32 + (E + 255) / 256, 256, 0, stream>>>(W, wswz, edge, deg, E);
  scan_one<<<NB, 1024, 0, stream>>>(deg, rowstart, rsc, flags, N, NB);
  scatter_kernel<<<(E + 255) / 256, 256, 0, stream>>>(edge, rsc, sdst, E);
  gemm_mfma<<<(N + 63) / 64, 256, 0, stream>>>(x, wswz, a, h, s, t, N);
  agg_kernel<<<(N + 3) / 4, 256, 0, stream>>>(h, s, t, rowstart, sdst, out, N);
}

// Round 9
// 286.025 us; speedup vs baseline: 1.1466x; 1.1466x over previous
//
#include <hip/hip_runtime.h>
#include <hip/hip_fp16.h>

#define FDIM 256
#define ALPHA 0.2f

typedef _Float16 half8 __attribute__((ext_vector_type(8)));
typedef float floatx4 __attribute__((ext_vector_type(4)));

// ---- prep W (fp16 chunked W^T image) + edge histogram, fused ---------------
__global__ __launch_bounds__(256) void prep_hist(const float* __restrict__ W,
                                                 _Float16* __restrict__ wswz,
                                                 const int* __restrict__ edge,
                                                 int* __restrict__ deg, int E) {
  if (blockIdx.x < 32) {
    const int g = blockIdx.x * 256 + threadIdx.x;  // 0..8191
    const int kc = g >> 11, L = g & 2047;
    const int n = L >> 3, c = L & 7;
    half8 hv;
#pragma unroll
    for (int j = 0; j < 8; ++j)
      hv[j] = (_Float16)W[(size_t)(kc * 64 + c * 8 + j) * 256 + n];
    *(half8*)(wswz + (size_t)g * 8) = hv;
  } else {
    const int e = (blockIdx.x - 32) * 256 + threadIdx.x;
    if (e < E) atomicAdd(&deg[edge[e]], 1);
  }
}

// ---- GEMM h = x@W, MFMA fp16; epilogue transposes via LDS for wide stores --
#define HT_STRIDE 264
__global__ __launch_bounds__(256) void gemm_mfma(
    const float* __restrict__ x, const _Float16* __restrict__ wswz,
    const float* __restrict__ a, _Float16* __restrict__ h,
    float* __restrict__ s, float* __restrict__ t, int M) {
  __shared__ __align__(16) _Float16 smem[64 * HT_STRIDE];  // 33.8 KB
  _Float16* As = smem;
  const int tid = threadIdx.x;
  const int w = tid >> 6, l = tid & 63;
  const int l15 = l & 15, q = l >> 4;
  const int row0 = blockIdx.x * 64;

  floatx4 acc[4][4];
#pragma unroll
  for (int mt = 0; mt < 4; ++mt)
#pragma unroll
    for (int nt = 0; nt < 4; ++nt) acc[mt][nt] = (floatx4){0.f, 0.f, 0.f, 0.f};

  const int id0 = tid, id1 = 256 + tid;
  const int m0 = id0 >> 3, c0 = (id0 & 7) ^ (m0 & 7);
  const int m1 = id1 >> 3, c1 = (id1 & 7) ^ (m1 & 7);
  const int r0 = row0 + m0, r1 = row0 + m1;

  float4 pf[2][2];
  auto loadA = [&](int kc) {
    pf[0][0] = pf[0][1] = pf[1][0] = pf[1][1] = make_float4(0.f, 0.f, 0.f, 0.f);
    if (r0 < M) {
      const float4* p = (const float4*)(x + (size_t)r0 * 256 + kc * 64 + c0 * 8);
      pf[0][0] = p[0];
      pf[0][1] = p[1];
    }
    if (r1 < M) {
      const float4* p = (const float4*)(x + (size_t)r1 * 256 + kc * 64 + c1 * 8);
      pf[1][0] = p[0];
      pf[1][1] = p[1];
    }
  };
  auto storeA = [&]() {
#pragma unroll
    for (int hf = 0; hf < 2; ++hf) {
      half8 hv;
      hv[0] = (_Float16)pf[hf][0].x; hv[1] = (_Float16)pf[hf][0].y;
      hv[2] = (_Float16)pf[hf][0].z; hv[3] = (_Float16)pf[hf][0].w;
      hv[4] = (_Float16)pf[hf][1].x; hv[5] = (_Float16)pf[hf][1].y;
      hv[6] = (_Float16)pf[hf][1].z; hv[7] = (_Float16)pf[hf][1].w;
      *(half8*)(As + (size_t)(hf * 256 + tid) * 8) = hv;
    }
  };

  loadA(0);
  for (int kc = 0; kc < 4; ++kc) {
    storeA();
    half8 bf[2][4];
#pragma unroll
    for (int ks = 0; ks < 2; ++ks) {
      const int c = ks * 4 + q;
#pragma unroll
      for (int nt = 0; nt < 4; ++nt) {
        const int n = w * 64 + nt * 16 + l15;
        bf[ks][nt] = *(const half8*)(wswz + (size_t)(kc * 2048 + n * 8 + c) * 8);
      }
    }
    __syncthreads();
    if (kc < 3) loadA(kc + 1);
#pragma unroll
    for (int ks = 0; ks < 2; ++ks) {
      const int c = ks * 4 + q;
      half8 af[4];
#pragma unroll
      for (int mt = 0; mt < 4; ++mt) {
        const int m = mt * 16 + l15;
        af[mt] = *(const half8*)(As + (size_t)(m * 8 + (c ^ (m & 7))) * 8);
      }
#pragma unroll
      for (int mt = 0; mt < 4; ++mt)
#pragma unroll
        for (int nt = 0; nt < 4; ++nt)
          acc[mt][nt] = __builtin_amdgcn_mfma_f32_16x16x32_f16(
              af[mt], bf[ks][nt], acc[mt][nt], 0, 0, 0);
    }
    __syncthreads();
  }

  // epilogue: C/D -> LDS row-major -> coalesced 16B stores
#pragma unroll
  for (int mt = 0; mt < 4; ++mt)
#pragma unroll
    for (int nt = 0; nt < 4; ++nt)
#pragma unroll
      for (int r = 0; r < 4; ++r)
        smem[(size_t)(mt * 16 + q * 4 + r) * HT_STRIDE + w * 64 + nt * 16 +
             l15] = (_Float16)acc[mt][nt][r];
  __syncthreads();

  const int w8 = tid >> 5;
  const int colh = (tid & 31) * 8;
#pragma unroll
  for (int p = 0; p < 8; ++p) {
    const int rl = p * 8 + w8;
    const int row = row0 + rl;
    if (row < M)
      *(half8*)(h + (size_t)row * 256 + colh) =
          *(const half8*)(smem + (size_t)rl * HT_STRIDE + colh);
  }

  // s/t from LDS tile
  const int r8 = tid >> 2, seg = tid & 3;
  float sp = 0.f, tp = 0.f;
#pragma unroll
  for (int c8 = 0; c8 < 8; ++c8) {
    const int col = seg * 64 + c8 * 8;
    const half8 hv = *(const half8*)(smem + (size_t)r8 * HT_STRIDE + col);
    const float4 a0 = *(const float4*)(a + col);
    const float4 a1 = *(const float4*)(a + col + 4);
    const float4 b0 = *(const float4*)(a + 256 + col);
    const float4 b1 = *(const float4*)(a + 256 + col + 4);
    sp += (float)hv[0] * a0.x + (float)hv[1] * a0.y + (float)hv[2] * a0.z +
          (float)hv[3] * a0.w + (float)hv[4] * a1.x + (float)hv[5] * a1.y +
          (float)hv[6] * a1.z + (float)hv[7] * a1.w;
    tp += (float)hv[0] * b0.x + (float)hv[1] * b0.y + (float)hv[2] * b0.z +
          (float)hv[3] * b0.w + (float)hv[4] * b1.x + (float)hv[5] * b1.y +
          (float)hv[6] * b1.z + (float)hv[7] * b1.w;
  }
  sp += __shfl_xor(sp, 1);
  sp += __shfl_xor(sp, 2);
  tp += __shfl_xor(tp, 1);
  tp += __shfl_xor(tp, 2);
  if (seg == 0 && row0 + r8 < M) {
    s[row0 + r8] = sp;
    t[row0 + r8] = tp;
  }
}

// ---- multi-block scan (3 launches, parallel combine — no serial chain) -----
__global__ __launch_bounds__(1024) void scan1(const int* __restrict__ deg,
                                              int* __restrict__ rowstart,
                                              int* __restrict__ bsum, int n) {
  const int tid = threadIdx.x;
  const int i = blockIdx.x * 1024 + tid;
  const int val = (i < n) ? deg[i] : 0;
  const int lane = tid & 63, wv = tid >> 6;
  int v = val;
#pragma unroll
  for (int off = 1; off < 64; off <<= 1) {
    const int o = __shfl_up(v, off);
    if (lane >= off) v += o;
  }
  __shared__ int wsum[16];
  __shared__ int woff[16];
  if (lane == 63) wsum[wv] = v;
  __syncthreads();
  if (tid < 16) {
    int wv2 = wsum[tid];
#pragma unroll
    for (int off = 1; off < 16; off <<= 1) {
      const int o = __shfl_up(wv2, off);
      if (tid >= off) wv2 += o;
    }
    woff[tid] = wv2;
  }
  __syncthreads();
  const int incl = v + (wv ? woff[wv - 1] : 0);
  if (i < n) rowstart[i] = incl - val;
  if (tid == 1023) bsum[blockIdx.x] = woff[15];
}

__global__ __launch_bounds__(64) void scan2(const int* __restrict__ bsum,
                                            int* __restrict__ boff,
                                            int* __restrict__ rowstart, int nb,
                                            int n) {
  const int tid = threadIdx.x;
  int v = (tid < nb) ? bsum[tid] : 0;
#pragma unroll
  for (int off = 1; off < 64; off <<= 1) {
    const int o = __shfl_up(v, off);
    if (tid >= off) v += o;
  }
  if (tid < nb) boff[tid] = v;
  if (tid == nb - 1) rowstart[n] = v;
}

// scan3: finalize rowstart AND emit rsc (cursor copy for scatter's atomicAdd)
__global__ __launch_bounds__(1024) void scan3(int* __restrict__ rowstart,
                                              int* __restrict__ rsc,
                                              const int* __restrict__ boff,
                                              int n) {
  const int i = blockIdx.x * 1024 + threadIdx.x;
  if (i < n) {
    const int v = rowstart[i] + (blockIdx.x ? boff[blockIdx.x - 1] : 0);
    rowstart[i] = v;
    rsc[i] = v;
  }
}

// ---- scatter: pure CSR permutation (no s/t, 4B payload) --------------------
__global__ void scatter_kernel(const int* __restrict__ edge,
                               int* __restrict__ rsc, int* __restrict__ sdst,
                               int E) {
  const int e = blockIdx.x * 256 + threadIdx.x;
  if (e < E) {
    const int src = edge[e];
    const int dst = edge[E + e];
    const int pos = atomicAdd(&rsc[src], 1);
    sdst[pos] = dst;
  }
}

// ---- aggregation: wave = 2 edges/iter, lane = 8 features; e computed inline
__global__ __launch_bounds__(256) void agg_kernel(
    const _Float16* __restrict__ h, const float* __restrict__ s,
    const float* __restrict__ t, const int* __restrict__ rowstart,
    const int* __restrict__ sdst, float* __restrict__ out, int n) {
  const int w = threadIdx.x >> 6, l = threadIdx.x & 63;
  const int row = blockIdx.x * 4 + w;
  if (row >= n) return;
  const int start = rowstart[row], end = rowstart[row + 1];
  const float srow = s[row];
  const int half = l >> 5;           // 0: edge j, 1: edge j+1
  const int lh = l & 31;             // lane within half
  const size_t fo = (size_t)lh * 8;  // 8 features = 16 B
  float acc[8] = {};
  float rs = 0.f;
  int j = start;
  for (; j + 8 <= end; j += 8) {
#pragma unroll
    for (int u = 0; u < 4; ++u) {
      const int d = sdst[j + u * 2 + half];
      const float logit = srow + t[d];
      const float lr = logit > 0.f ? logit : ALPHA * logit;
      const float e = __expf(-lr);
      const half8 v = *(const half8*)(h + (size_t)d * 256 + fo);
      rs += e;
#pragma unroll
      for (int k = 0; k < 8; ++k) acc[k] += e * (float)v[k];
    }
  }
  for (; j < end; j += 2) {
    const int idx = j + half;
    const bool valid = idx < end;
    const int d = valid ? sdst[idx] : 0;
    const float logit = srow + t[d];
    const float lr = logit > 0.f ? logit : ALPHA * logit;
    const float e = valid ? __expf(-lr) : 0.f;
    const half8 v = *(const half8*)(h + (size_t)d * 256 + fo);
    rs += e;
#pragma unroll
    for (int k = 0; k < 8; ++k) acc[k] += e * (float)v[k];
  }
  rs += __shfl_xor(rs, 32);
#pragma unroll
  for (int k = 0; k < 8; ++k) acc[k] += __shfl_xor(acc[k], 32);
  const float inv = 1.f / rs;
  float4 o;
#pragma unroll
  for (int k = 0; k < 4; ++k) {
    const float vv = acc[half * 4 + k] * inv;
    (&o.x)[k] = vv > 0.f ? vv : 0.f;
  }
  *(float4*)(out + (size_t)row * 256 + lh * 8 + half * 4) = o;
}

extern "C" void kernel_launch(void* const* d_in, const int* in_sizes, int n_in,
                              void* d_out, int out_size, void* d_ws,
                              size_t ws_size, hipStream_t stream) {
  const float* x = (const float*)d_in[0];
  const int* edge = (const int*)d_in[1];
  const float* W = (const float*)d_in[2];
  const float* a = (const float*)d_in[3];
  float* out = (float*)d_out;
  const int N = in_sizes[0] / FDIM;  // 50000
  const int E = in_sizes[1] / 2;     // 850000
  const int NB = (N + 1023) / 1024;  // 49

  _Float16* h = (_Float16*)d_ws;          // N*256 fp16
  _Float16* wswz = h + (size_t)N * FDIM;  // 65536 halves (128 KB)
  float* s = (float*)(wswz + 8192 * 8);   // N
  float* t = s + N;                       // N
  int* deg = (int*)(t + N);               // N
  int* rsc = deg + N;                     // N
  int* rowstart = rsc + N;                // N+2
  int* bsum = rowstart + N + 2;           // 64
  int* boff = bsum + 64;                  // 64
  int* sdst = boff + 64;                  // E

  hipMemsetAsync(deg, 0, (size_t)N * sizeof(int), stream);

  prep_hist<<<32 + (E + 255) / 256, 256, 0, stream>>>(W, wswz, edge, deg, E);
  gemm_mfma<<<(N + 63) / 64, 256, 0, stream>>>(x, wswz, a, h, s, t, N);
  scan1<<<NB, 1024, 0, stream>>>(deg, rowstart, bsum, N);
  scan2<<<1, 64, 0, stream>>>(bsum, boff, rowstart, NB, N);
  scan3<<<NB, 1024, 0, stream>>>(rowstart, rsc, boff, N);
  scatter_kernel<<<(E + 255) / 256, 256, 0, stream>>>(edge, rsc, sdst, E);
  agg_kernel<<<(N + 3) / 4, 256, 0, stream>>>(h, s, t, rowstart, sdst, out, N);
}